// Round 1
// baseline (530.587 us; speedup 1.0000x reference)
//
#include <hip/hip_runtime.h>
#include <math.h>

#define TLEN 4096
#define BD   1024
#define HDIM 64
#define NB   4

// ---------------------------------------------------------------------------
// Kernel 1: QKV projection.  out[t][o] = sum_k x[t][k] * w[o][k]
// GEMM M=B*T=16384, N=64, K=1024.  grid=(M/64, 3), block=256.
// 64x64 tile, 4x4 per-thread register block, BK=32, LDS operands transposed
// to [k][row] so the inner loop does two ds_read_b128 per 16 FMA.
// ---------------------------------------------------------------------------
__global__ __launch_bounds__(256) void qkv_kernel(
    const float* __restrict__ x,
    const float* __restrict__ wq,
    const float* __restrict__ wk,
    const float* __restrict__ wv,
    float* __restrict__ Qo,
    float* __restrict__ Ko,
    float* __restrict__ Vo)
{
    const float* w;
    float* out;
    if (blockIdx.y == 0)      { w = wq; out = Qo; }
    else if (blockIdx.y == 1) { w = wk; out = Ko; }
    else                      { w = wv; out = Vo; }

    const int row0 = blockIdx.x * 64;

    __shared__ float xs[32][68];   // [k][token]   (+4 pad keeps 16B alignment)
    __shared__ float wsh[32][68];  // [k][out]

    const int tid = threadIdx.x;
    const int r4  = tid >> 4;      // 0..15 -> token rows r4*4..+3
    const int c4  = tid & 15;      // 0..15 -> out cols  c4*4..+3
    const int kk  = (tid & 7) * 4; // k offset for loads
    const int rr  = tid >> 3;      // 0..31  row for loads

    float acc[4][4] = {};

    for (int k0 = 0; k0 < BD; k0 += 32) {
        float4 a0 = *(const float4*)&x[(size_t)(row0 + rr)      * BD + k0 + kk];
        float4 a1 = *(const float4*)&x[(size_t)(row0 + rr + 32) * BD + k0 + kk];
        float4 b0 = *(const float4*)&w[(size_t)(rr)      * BD + k0 + kk];
        float4 b1 = *(const float4*)&w[(size_t)(rr + 32) * BD + k0 + kk];
        __syncthreads();  // previous tile fully consumed
        xs[kk+0][rr]    = a0.x; xs[kk+1][rr]    = a0.y; xs[kk+2][rr]    = a0.z; xs[kk+3][rr]    = a0.w;
        xs[kk+0][rr+32] = a1.x; xs[kk+1][rr+32] = a1.y; xs[kk+2][rr+32] = a1.z; xs[kk+3][rr+32] = a1.w;
        wsh[kk+0][rr]    = b0.x; wsh[kk+1][rr]    = b0.y; wsh[kk+2][rr]    = b0.z; wsh[kk+3][rr]    = b0.w;
        wsh[kk+0][rr+32] = b1.x; wsh[kk+1][rr+32] = b1.y; wsh[kk+2][rr+32] = b1.z; wsh[kk+3][rr+32] = b1.w;
        __syncthreads();

        #pragma unroll 8
        for (int k = 0; k < 32; ++k) {
            float4 a = *(const float4*)&xs[k][r4 * 4];
            float4 b = *(const float4*)&wsh[k][c4 * 4];
            float av[4] = {a.x, a.y, a.z, a.w};
            float bv[4] = {b.x, b.y, b.z, b.w};
            #pragma unroll
            for (int i = 0; i < 4; ++i)
                #pragma unroll
                for (int j = 0; j < 4; ++j)
                    acc[i][j] = fmaf(av[i], bv[j], acc[i][j]);
        }
    }

    #pragma unroll
    for (int i = 0; i < 4; ++i) {
        float4 r;
        r.x = acc[i][0]; r.y = acc[i][1]; r.z = acc[i][2]; r.w = acc[i][3];
        *(float4*)&out[(size_t)(row0 + r4 * 4 + i) * HDIM + c4 * 4] = r;
    }
}

// ---------------------------------------------------------------------------
// Kernel 2: flash attention (fp32, online softmax).
// grid=(T/64, B), block=256.  64-query x 64-key tiles, HD=64.
// Thread (r4,c4) owns a 4x4 block of S and of O.
// NOTE: Q and out may alias (Q lives in d_out) -> no __restrict__ on them.
// ---------------------------------------------------------------------------
__global__ __launch_bounds__(256) void attn_kernel(
    const float* Q,
    const float* __restrict__ K,
    const float* __restrict__ V,
    float* out)
{
    const int b  = blockIdx.y;
    const int q0 = blockIdx.x * 64;
    const float* Qb = Q + (size_t)b * TLEN * HDIM;
    const float* Kb = K + (size_t)b * TLEN * HDIM;
    const float* Vb = V + (size_t)b * TLEN * HDIM;

    __shared__ float qs[64][68];  // [d][qrow]
    __shared__ float ks[64][68];  // [d][key]
    __shared__ float vs[64][68];  // [key][d]
    __shared__ float ps[64][68];  // [key][qrow]

    const int tid = threadIdx.x;
    const int r4  = tid >> 4;        // 0..15
    const int c4  = tid & 15;        // 0..15
    const int dd  = (tid & 15) * 4;  // load: d offset
    const int rr  = tid >> 4;        // load: row 0..15 (x4 passes)

    // stage Q tile, transposed to [d][row]
    #pragma unroll
    for (int p = 0; p < 4; ++p) {
        float4 a = *(const float4*)&Qb[(size_t)(q0 + rr + p * 16) * HDIM + dd];
        qs[dd+0][rr + p*16] = a.x; qs[dd+1][rr + p*16] = a.y;
        qs[dd+2][rr + p*16] = a.z; qs[dd+3][rr + p*16] = a.w;
    }

    float m[4], l[4], o[4][4];
    #pragma unroll
    for (int i = 0; i < 4; ++i) {
        m[i] = -INFINITY; l[i] = 0.f;
        #pragma unroll
        for (int j = 0; j < 4; ++j) o[i][j] = 0.f;
    }

    for (int s0 = 0; s0 < TLEN; s0 += 64) {
        __syncthreads();  // previous tile's S/PV reads done
        #pragma unroll
        for (int p = 0; p < 4; ++p) {
            float4 a = *(const float4*)&Kb[(size_t)(s0 + rr + p * 16) * HDIM + dd];
            ks[dd+0][rr + p*16] = a.x; ks[dd+1][rr + p*16] = a.y;
            ks[dd+2][rr + p*16] = a.z; ks[dd+3][rr + p*16] = a.w;
            float4 v = *(const float4*)&Vb[(size_t)(s0 + rr + p * 16) * HDIM + dd];
            *(float4*)&vs[rr + p*16][dd] = v;
        }
        __syncthreads();

        // S = Q @ K^T for this tile
        float sacc[4][4] = {};
        #pragma unroll 8
        for (int k = 0; k < 64; ++k) {
            float4 a  = *(const float4*)&qs[k][r4 * 4];
            float4 bb = *(const float4*)&ks[k][c4 * 4];
            float av[4] = {a.x, a.y, a.z, a.w};
            float bv[4] = {bb.x, bb.y, bb.z, bb.w};
            #pragma unroll
            for (int i = 0; i < 4; ++i)
                #pragma unroll
                for (int j = 0; j < 4; ++j)
                    sacc[i][j] = fmaf(av[i], bv[j], sacc[i][j]);
        }

        // online softmax (scale = 1/sqrt(64) = 0.125)
        float pr[4][4];
        #pragma unroll
        for (int i = 0; i < 4; ++i) {
            float tm = fmaxf(fmaxf(sacc[i][0], sacc[i][1]),
                             fmaxf(sacc[i][2], sacc[i][3])) * 0.125f;
            tm = fmaxf(tm, __shfl_xor(tm, 1));
            tm = fmaxf(tm, __shfl_xor(tm, 2));
            tm = fmaxf(tm, __shfl_xor(tm, 4));
            tm = fmaxf(tm, __shfl_xor(tm, 8));
            const float newm  = fmaxf(m[i], tm);
            const float alpha = __expf(m[i] - newm);
            float rs = 0.f;
            #pragma unroll
            for (int j = 0; j < 4; ++j) {
                pr[i][j] = __expf(fmaf(sacc[i][j], 0.125f, -newm));
                rs += pr[i][j];
            }
            rs += __shfl_xor(rs, 1);
            rs += __shfl_xor(rs, 2);
            rs += __shfl_xor(rs, 4);
            rs += __shfl_xor(rs, 8);
            l[i] = l[i] * alpha + rs;
            m[i] = newm;
            #pragma unroll
            for (int j = 0; j < 4; ++j) o[i][j] *= alpha;
        }

        // P -> LDS transposed to [key][qrow]  (safe: ps last read before loop-top sync)
        #pragma unroll
        for (int i = 0; i < 4; ++i)
            #pragma unroll
            for (int j = 0; j < 4; ++j)
                ps[c4 * 4 + j][r4 * 4 + i] = pr[i][j];
        __syncthreads();

        // O += P @ V
        #pragma unroll 8
        for (int s = 0; s < 64; ++s) {
            float4 p4 = *(const float4*)&ps[s][r4 * 4];
            float4 v4 = *(const float4*)&vs[s][c4 * 4];
            float pv[4] = {p4.x, p4.y, p4.z, p4.w};
            float vv[4] = {v4.x, v4.y, v4.z, v4.w};
            #pragma unroll
            for (int i = 0; i < 4; ++i)
                #pragma unroll
                for (int j = 0; j < 4; ++j)
                    o[i][j] = fmaf(pv[i], vv[j], o[i][j]);
        }
    }

    #pragma unroll
    for (int i = 0; i < 4; ++i) {
        const float inv = 1.0f / l[i];
        float4 r;
        r.x = o[i][0] * inv; r.y = o[i][1] * inv;
        r.z = o[i][2] * inv; r.w = o[i][3] * inv;
        *(float4*)&out[(size_t)(b * TLEN + q0 + r4 * 4 + i) * HDIM + c4 * 4] = r;
    }
}

// ---------------------------------------------------------------------------
extern "C" void kernel_launch(void* const* d_in, const int* in_sizes, int n_in,
                              void* d_out, int out_size, void* d_ws, size_t ws_size,
                              hipStream_t stream)
{
    (void)in_sizes; (void)n_in; (void)out_size; (void)ws_size;
    const float* x  = (const float*)d_in[0];
    const float* wq = (const float*)d_in[1];
    const float* wk = (const float*)d_in[2];
    const float* wv = (const float*)d_in[3];
    float* out  = (float*)d_out;

    // K, V in workspace (8 MiB); Q lives in d_out (each attention block reads
    // only its own Q rows into LDS before overwriting them at the end).
    float* Kbuf = (float*)d_ws;
    float* Vbuf = Kbuf + (size_t)NB * TLEN * HDIM;
    float* Qbuf = out;

    dim3 gProj(NB * TLEN / 64, 3);
    qkv_kernel<<<gProj, 256, 0, stream>>>(x, wq, wk, wv, Qbuf, Kbuf, Vbuf);

    dim3 gAttn(TLEN / 64, NB);
    attn_kernel<<<gAttn, 256, 0, stream>>>(Qbuf, Kbuf, Vbuf, out);
}

// Round 2
// 237.982 us; speedup vs baseline: 2.2295x; 2.2295x over previous
//
#include <hip/hip_runtime.h>
#include <math.h>

#define TLEN 4096
#define BD   1024
#define HDIM 64
#define NB   4

typedef __attribute__((ext_vector_type(8))) short bf16x8;
typedef __attribute__((ext_vector_type(4))) float f32x4;

__device__ __forceinline__ unsigned short f2bf(float f) {
    union { float f; unsigned u; } v; v.f = f;
    unsigned r = v.u + 0x7FFF + ((v.u >> 16) & 1);   // RNE
    return (unsigned short)(r >> 16);
}

__device__ __forceinline__ void pack8(const float4& a, const float4& b,
                                      unsigned short* dst) {
    unsigned short t[8] = {f2bf(a.x), f2bf(a.y), f2bf(a.z), f2bf(a.w),
                           f2bf(b.x), f2bf(b.y), f2bf(b.z), f2bf(b.w)};
    *(uint4*)dst = *(const uint4*)t;
}

// ---------------------------------------------------------------------------
// Kernel 1: QKV projection, bf16 MFMA.  x[16384][1024] fp32 -> Q,K bf16
// [t][64] and V transposed bf16 [b][64][4096].  grid=256, block=256.
// Block = 64 rows x 192 cols (Q|K|V), wave = 16 rows.  x read ONCE.
// ---------------------------------------------------------------------------
__global__ __launch_bounds__(256) void qkv_kernel(
    const float* __restrict__ x,
    const float* __restrict__ wq,
    const float* __restrict__ wk,
    const float* __restrict__ wv,
    unsigned short* __restrict__ Qb,
    unsigned short* __restrict__ Kb,
    unsigned short* __restrict__ Vt)
{
    const int r0 = blockIdx.x * 64;

    __shared__ __align__(16) unsigned short xs[64][40];    // [row][k], pad->20dw
    __shared__ __align__(16) unsigned short wsh[192][40];  // [outdim][k]

    const int tid  = threadIdx.x;
    const int lane = tid & 63;
    const int wid  = tid >> 6;
    const int g    = lane >> 4;
    const int c    = lane & 15;
    const int lrow = tid >> 2;        // 0..63
    const int kc   = (tid & 3) * 8;   // 0,8,16,24

    const float* wm[3] = {wq, wk, wv};

    f32x4 acc[12];
    #pragma unroll
    for (int t = 0; t < 12; ++t) acc[t] = (f32x4){0.f, 0.f, 0.f, 0.f};

    // preload first k-step
    float4 xa, xb, wa[3], wb[3];
    {
        xa = *(const float4*)&x[(size_t)(r0 + lrow) * BD + kc];
        xb = *(const float4*)&x[(size_t)(r0 + lrow) * BD + kc + 4];
        #pragma unroll
        for (int m = 0; m < 3; ++m) {
            wa[m] = *(const float4*)&wm[m][(size_t)lrow * BD + kc];
            wb[m] = *(const float4*)&wm[m][(size_t)lrow * BD + kc + 4];
        }
    }

    for (int k0 = 0; k0 < BD; k0 += 32) {
        __syncthreads();   // previous tile consumed
        pack8(xa, xb, &xs[lrow][kc]);
        #pragma unroll
        for (int m = 0; m < 3; ++m) pack8(wa[m], wb[m], &wsh[m * 64 + lrow][kc]);
        __syncthreads();

        // issue next tile's loads early (clamped address on last iter)
        const int kn = (k0 + 32 < BD) ? k0 + 32 : k0;
        xa = *(const float4*)&x[(size_t)(r0 + lrow) * BD + kn + kc];
        xb = *(const float4*)&x[(size_t)(r0 + lrow) * BD + kn + kc + 4];
        #pragma unroll
        for (int m = 0; m < 3; ++m) {
            wa[m] = *(const float4*)&wm[m][(size_t)lrow * BD + kn + kc];
            wb[m] = *(const float4*)&wm[m][(size_t)lrow * BD + kn + kc + 4];
        }

        bf16x8 aF = *(const bf16x8*)&xs[wid * 16 + c][g * 8];
        #pragma unroll
        for (int t = 0; t < 12; ++t) {
            bf16x8 bF = *(const bf16x8*)&wsh[c + 16 * t][g * 8];
            acc[t] = __builtin_amdgcn_mfma_f32_16x16x32_bf16(aF, bF, acc[t], 0, 0, 0);
        }
    }

    // epilogue: C frag row = g*4+i (wave-local), col = c+16t
    const int   bb    = r0 / TLEN;
    const int   trow0 = (r0 % TLEN) + wid * 16 + g * 4;
    const size_t grow = (size_t)(r0 + wid * 16 + g * 4);
    #pragma unroll
    for (int t = 0; t < 4; ++t)
        #pragma unroll
        for (int i = 0; i < 4; ++i)
            Qb[(grow + i) * HDIM + c + 16 * t] = f2bf(acc[t][i]);
    #pragma unroll
    for (int t = 0; t < 4; ++t)
        #pragma unroll
        for (int i = 0; i < 4; ++i)
            Kb[(grow + i) * HDIM + c + 16 * t] = f2bf(acc[4 + t][i]);
    #pragma unroll
    for (int t = 0; t < 4; ++t)
        #pragma unroll
        for (int i = 0; i < 4; ++i)
            Vt[(size_t)bb * HDIM * TLEN + (size_t)(c + 16 * t) * TLEN + trow0 + i]
                = f2bf(acc[8 + t][i]);
}

// ---------------------------------------------------------------------------
// Kernel 2: bf16 MFMA flash attention.  grid=(64, NB), block=256 (4 waves).
// Q tile 64 rows; wave = 16 rows; K tile 64.  16x16x32 MFMA.
// A layout: m=lane&15, k=(lane>>4)*8+j.  B: n=lane&15, same k.
// C/D: col=lane&15, row=(lane>>4)*4+reg.
// ---------------------------------------------------------------------------
__global__ __launch_bounds__(256) void attn_kernel(
    const unsigned short* __restrict__ Qb,
    const unsigned short* __restrict__ Kb,
    const unsigned short* __restrict__ Vt,
    float* __restrict__ out)
{
    const int b  = blockIdx.y;
    const int q0 = blockIdx.x * 64;
    const unsigned short* Qp = Qb + (size_t)b * TLEN * HDIM;
    const unsigned short* Kp = Kb + (size_t)b * TLEN * HDIM;
    const unsigned short* Vp = Vt + (size_t)b * HDIM * TLEN;

    __shared__ __align__(16) unsigned short qs[64][72];      // [qrow][d]
    __shared__ __align__(16) unsigned short ks[64][72];      // [key][d]
    __shared__ __align__(16) unsigned short vs[64][72];      // [d][key] (Vt tile)
    __shared__ __align__(16) unsigned short pp[4][16][72];   // per-wave P [qrow][key]

    const int tid  = threadIdx.x;
    const int lane = tid & 63;
    const int w    = tid >> 6;
    const int g    = lane >> 4;
    const int c    = lane & 15;
    const int srow = tid >> 2;        // staging row 0..63
    const int skc  = (tid & 3) * 16;  // 0,16,32,48

    // stage Q tile
    {
        uint4 a0 = *(const uint4*)&Qp[(size_t)(q0 + srow) * HDIM + skc];
        uint4 a1 = *(const uint4*)&Qp[(size_t)(q0 + srow) * HDIM + skc + 8];
        *(uint4*)&qs[srow][skc]     = a0;
        *(uint4*)&qs[srow][skc + 8] = a1;
    }
    __syncthreads();
    bf16x8 qA0 = *(const bf16x8*)&qs[w * 16 + c][g * 8];
    bf16x8 qA1 = *(const bf16x8*)&qs[w * 16 + c][32 + g * 8];

    float mrow[4], lsum[4];
    f32x4 oacc[4];
    #pragma unroll
    for (int i = 0; i < 4; ++i) { mrow[i] = -INFINITY; lsum[i] = 0.f; }
    #pragma unroll
    for (int t = 0; t < 4; ++t) oacc[t] = (f32x4){0.f, 0.f, 0.f, 0.f};

    // preload first K/V tile
    uint4 k0v = *(const uint4*)&Kp[(size_t)srow * HDIM + skc];
    uint4 k1v = *(const uint4*)&Kp[(size_t)srow * HDIM + skc + 8];
    uint4 v0v = *(const uint4*)&Vp[(size_t)srow * TLEN + skc];
    uint4 v1v = *(const uint4*)&Vp[(size_t)srow * TLEN + skc + 8];

    for (int s0 = 0; s0 < TLEN; s0 += 64) {
        __syncthreads();   // everyone done with previous ks/vs
        *(uint4*)&ks[srow][skc]     = k0v;
        *(uint4*)&ks[srow][skc + 8] = k1v;
        *(uint4*)&vs[srow][skc]     = v0v;
        *(uint4*)&vs[srow][skc + 8] = v1v;
        __syncthreads();

        // issue next tile's loads early (clamped on last iter)
        const int sn = (s0 + 64 < TLEN) ? s0 + 64 : s0;
        k0v = *(const uint4*)&Kp[(size_t)(sn + srow) * HDIM + skc];
        k1v = *(const uint4*)&Kp[(size_t)(sn + srow) * HDIM + skc + 8];
        v0v = *(const uint4*)&Vp[(size_t)srow * TLEN + sn + skc];
        v1v = *(const uint4*)&Vp[(size_t)srow * TLEN + sn + skc + 8];

        // S = Q K^T  (wave's 16 rows x 64 keys)
        f32x4 sacc[4];
        #pragma unroll
        for (int t = 0; t < 4; ++t) sacc[t] = (f32x4){0.f, 0.f, 0.f, 0.f};
        #pragma unroll
        for (int t = 0; t < 4; ++t) {
            bf16x8 kB0 = *(const bf16x8*)&ks[c + 16 * t][g * 8];
            bf16x8 kB1 = *(const bf16x8*)&ks[c + 16 * t][32 + g * 8];
            sacc[t] = __builtin_amdgcn_mfma_f32_16x16x32_bf16(qA0, kB0, sacc[t], 0, 0, 0);
            sacc[t] = __builtin_amdgcn_mfma_f32_16x16x32_bf16(qA1, kB1, sacc[t], 0, 0, 0);
        }

        // online softmax; C-frag row = g*4+i, reduce over 16-lane col groups
        #pragma unroll
        for (int i = 0; i < 4; ++i) {
            float tm = fmaxf(fmaxf(sacc[0][i], sacc[1][i]),
                             fmaxf(sacc[2][i], sacc[3][i])) * 0.125f;
            tm = fmaxf(tm, __shfl_xor(tm, 1));
            tm = fmaxf(tm, __shfl_xor(tm, 2));
            tm = fmaxf(tm, __shfl_xor(tm, 4));
            tm = fmaxf(tm, __shfl_xor(tm, 8));
            const float newm  = fmaxf(mrow[i], tm);
            const float alpha = __expf(mrow[i] - newm);
            float pr[4];
            float rs = 0.f;
            #pragma unroll
            for (int t = 0; t < 4; ++t) {
                pr[t] = __expf(fmaf(sacc[t][i], 0.125f, -newm));
                rs += pr[t];
            }
            rs += __shfl_xor(rs, 1);
            rs += __shfl_xor(rs, 2);
            rs += __shfl_xor(rs, 4);
            rs += __shfl_xor(rs, 8);
            lsum[i] = lsum[i] * alpha + rs;
            mrow[i] = newm;
            #pragma unroll
            for (int t = 0; t < 4; ++t) oacc[t][i] *= alpha;
            // P -> wave-private LDS (row-major [qrow][key]); no barrier needed
            #pragma unroll
            for (int t = 0; t < 4; ++t)
                pp[w][g * 4 + i][c + 16 * t] = f2bf(pr[t]);
        }

        // O += P V   (A = P from pp, B = V from vs[d][key])
        bf16x8 pA0 = *(const bf16x8*)&pp[w][c][g * 8];
        bf16x8 pA1 = *(const bf16x8*)&pp[w][c][32 + g * 8];
        #pragma unroll
        for (int t = 0; t < 4; ++t) {
            bf16x8 vB0 = *(const bf16x8*)&vs[c + 16 * t][g * 8];
            bf16x8 vB1 = *(const bf16x8*)&vs[c + 16 * t][32 + g * 8];
            oacc[t] = __builtin_amdgcn_mfma_f32_16x16x32_bf16(pA0, vB0, oacc[t], 0, 0, 0);
            oacc[t] = __builtin_amdgcn_mfma_f32_16x16x32_bf16(pA1, vB1, oacc[t], 0, 0, 0);
        }
    }

    // epilogue
    #pragma unroll
    for (int i = 0; i < 4; ++i) {
        const float inv = 1.0f / lsum[i];
        #pragma unroll
        for (int t = 0; t < 4; ++t)
            out[(size_t)(b * TLEN + q0 + w * 16 + g * 4 + i) * HDIM + c + 16 * t]
                = oacc[t][i] * inv;
    }
}

// ---------------------------------------------------------------------------
extern "C" void kernel_launch(void* const* d_in, const int* in_sizes, int n_in,
                              void* d_out, int out_size, void* d_ws, size_t ws_size,
                              hipStream_t stream)
{
    (void)in_sizes; (void)n_in; (void)out_size; (void)ws_size;
    const float* x  = (const float*)d_in[0];
    const float* wq = (const float*)d_in[1];
    const float* wk = (const float*)d_in[2];
    const float* wv = (const float*)d_in[3];
    float* out = (float*)d_out;

    // bf16 intermediates in workspace: Q,K [16384][64], Vt [4][64][4096] (2 MB each)
    unsigned short* Qbf = (unsigned short*)d_ws;
    unsigned short* Kbf = Qbf + (size_t)NB * TLEN * HDIM;
    unsigned short* Vtb = Kbf + (size_t)NB * TLEN * HDIM;

    qkv_kernel<<<dim3(NB * TLEN / 64), 256, 0, stream>>>(x, wq, wk, wv, Qbf, Kbf, Vtb);
    attn_kernel<<<dim3(TLEN / 64, NB), 256, 0, stream>>>(Qbf, Kbf, Vtb, out);
}